// Round 13
// baseline (408.962 us; speedup 1.0000x reference)
//
#include <hip/hip_runtime.h>

typedef __attribute__((ext_vector_type(8))) __bf16 bf16x8;
typedef __attribute__((ext_vector_type(4))) float f32x4;
typedef __attribute__((ext_vector_type(4))) unsigned int u32x4;
typedef __attribute__((ext_vector_type(4))) unsigned short u16x4;
typedef __attribute__((ext_vector_type(8))) unsigned short u16x8;

__device__ __forceinline__ unsigned short f2bf(float x) {
  unsigned u = __builtin_bit_cast(unsigned, x);
  u += 0x7fffu + ((u >> 16) & 1u);
  return (unsigned short)(u >> 16);
}
__device__ __forceinline__ float bf2f(unsigned short h) {
  unsigned u = ((unsigned)h) << 16;
  return __builtin_bit_cast(float, u);
}
__device__ __forceinline__ bf16x8 ld_frag(const unsigned short* p) {
  u32x4 u = *(const u32x4*)p;
  return __builtin_bit_cast(bf16x8, u);
}
__device__ __forceinline__ void gload_lds16(const unsigned short* g, unsigned short* l) {
  __builtin_amdgcn_global_load_lds(
      (const __attribute__((address_space(1))) void*)g,
      (__attribute__((address_space(3))) void*)l, 16, 0, 0);
}

// ---------------- f32 -> bf16 conversion (vectorized) ----------------
__global__ __launch_bounds__(256) void cvt_bf16(const float* __restrict__ in,
                                                unsigned short* __restrict__ out, int n4) {
  int i = blockIdx.x * 256 + threadIdx.x;
  if (i >= n4) return;
  f32x4 v = *((const f32x4*)in + i);
  u16x4 o;
  #pragma unroll
  for (int j = 0; j < 4; ++j) o[j] = f2bf(v[j]);
  *((u16x4*)out + i) = o;
}

// ---- 8-phase GEMM, 4M x 2N wave map (unchanged r12) ----
template <int MODE>
__global__ __launch_bounds__(512, 2) void gemm8p(const unsigned short* __restrict__ A,
                                                 const unsigned short* __restrict__ B,
                                                 void* __restrict__ Cv,
                                                 const float* __restrict__ cs,
                                                 const float* __restrict__ sn,
                                                 int M, int N, int K) {
  __shared__ __align__(16) unsigned short SM[57344];  // 112 KB
  const int nwg = gridDim.x;
  const int swz = (blockIdx.x & 7) * (nwg >> 3) + (blockIdx.x >> 3);
  const int bx = swz & 15, by = swz >> 4;      // M/256 == 16 for both GEMMs
  const int row0 = bx * 256, col0 = by * 192;
  const int tid = threadIdx.x;
  const int wave = tid >> 6, lane = tid & 63;
  const int g = lane >> 4, r = lane & 15;
  const int wm = (wave >> 1) * 64, wn = (wave & 1) * 96;
  const int NT = K >> 6;

  const unsigned short* Agb = A + (size_t)row0 * K;
  const unsigned short* Bgb = B + (size_t)col0 * K;

  f32x4 acc[4][6] = {};

  auto SU = [&](const unsigned short* src, unsigned short* dst, int u) {
    const int pos = u * 512 + tid;
    const int rw = pos >> 3, cc = pos & 7;
    gload_lds16(src + (size_t)rw * K + ((cc ^ (rw & 7)) * 8), dst + pos * 8);
  };
  auto LDA = [&](const unsigned short* base, int mi, int dk) {
    const int rw = wm + mi * 16 + r;
    return ld_frag(base + rw * 64 + (((dk * 4 + g) ^ (r & 7)) * 8));
  };
  auto LDB = [&](const unsigned short* base, int ni, int dk) {
    const int rw = wn + ni * 16 + r;
    return ld_frag(base + rw * 64 + (((dk * 4 + g) ^ (r & 7)) * 8));
  };

  SU(Agb, SM, 0); SU(Agb, SM, 1); SU(Agb, SM, 2); SU(Agb, SM, 3);
  SU(Bgb, SM + 16384, 0); SU(Bgb, SM + 16384, 1); SU(Bgb, SM + 16384, 2);
  __syncthreads();

  for (int t = 0; t < NT; ++t) {
    const int d = t & 1;
    const unsigned short* Ab = SM + d * 28672;
    const unsigned short* Bb = Ab + 16384;
    unsigned short* An = SM + (d ^ 1) * 28672;
    unsigned short* Bn = An + 16384;
    const unsigned short* Asrc = Agb + (t + 1) * 64;
    const unsigned short* Bsrc = Bgb + (t + 1) * 64;
    const bool pf = (t + 1 < NT);

    bf16x8 a0, a1, b[6];

    b[0] = LDB(Bb, 0, 0); b[1] = LDB(Bb, 1, 0); b[2] = LDB(Bb, 2, 0);
    b[3] = LDB(Bb, 3, 0); b[4] = LDB(Bb, 4, 0); b[5] = LDB(Bb, 5, 0);
    a0 = LDA(Ab, 0, 0); a1 = LDA(Ab, 1, 0);
    if (pf) { SU(Asrc, An, 0); SU(Asrc, An, 1); SU(Asrc, An, 2); }
    __builtin_amdgcn_s_barrier();
    asm volatile("s_waitcnt lgkmcnt(0)" ::: "memory");
    __builtin_amdgcn_sched_barrier(0);
    __builtin_amdgcn_s_setprio(1);
    #pragma unroll
    for (int n = 0; n < 6; ++n) {
      acc[0][n] = __builtin_amdgcn_mfma_f32_16x16x32_bf16(a0, b[n], acc[0][n], 0, 0, 0);
      acc[1][n] = __builtin_amdgcn_mfma_f32_16x16x32_bf16(a1, b[n], acc[1][n], 0, 0, 0);
    }
    __builtin_amdgcn_s_setprio(0);
    __builtin_amdgcn_s_barrier();

    a0 = LDA(Ab, 2, 0); a1 = LDA(Ab, 3, 0);
    if (pf) { SU(Asrc, An, 3); SU(Bsrc, Bn, 0); }
    __builtin_amdgcn_s_barrier();
    asm volatile("s_waitcnt lgkmcnt(0)" ::: "memory");
    __builtin_amdgcn_sched_barrier(0);
    __builtin_amdgcn_s_setprio(1);
    #pragma unroll
    for (int n = 0; n < 6; ++n) {
      acc[2][n] = __builtin_amdgcn_mfma_f32_16x16x32_bf16(a0, b[n], acc[2][n], 0, 0, 0);
      acc[3][n] = __builtin_amdgcn_mfma_f32_16x16x32_bf16(a1, b[n], acc[3][n], 0, 0, 0);
    }
    __builtin_amdgcn_s_setprio(0);
    __builtin_amdgcn_s_barrier();

    b[0] = LDB(Bb, 0, 1); b[1] = LDB(Bb, 1, 1); b[2] = LDB(Bb, 2, 1);
    b[3] = LDB(Bb, 3, 1); b[4] = LDB(Bb, 4, 1); b[5] = LDB(Bb, 5, 1);
    a0 = LDA(Ab, 0, 1); a1 = LDA(Ab, 1, 1);
    if (pf) { SU(Bsrc, Bn, 1); SU(Bsrc, Bn, 2); }
    __builtin_amdgcn_s_barrier();
    asm volatile("s_waitcnt lgkmcnt(0)" ::: "memory");
    __builtin_amdgcn_sched_barrier(0);
    __builtin_amdgcn_s_setprio(1);
    #pragma unroll
    for (int n = 0; n < 6; ++n) {
      acc[0][n] = __builtin_amdgcn_mfma_f32_16x16x32_bf16(a0, b[n], acc[0][n], 0, 0, 0);
      acc[1][n] = __builtin_amdgcn_mfma_f32_16x16x32_bf16(a1, b[n], acc[1][n], 0, 0, 0);
    }
    __builtin_amdgcn_s_setprio(0);
    __builtin_amdgcn_s_barrier();

    a0 = LDA(Ab, 2, 1); a1 = LDA(Ab, 3, 1);
    __builtin_amdgcn_s_barrier();
    asm volatile("s_waitcnt lgkmcnt(0)" ::: "memory");
    __builtin_amdgcn_sched_barrier(0);
    __builtin_amdgcn_s_setprio(1);
    #pragma unroll
    for (int n = 0; n < 6; ++n) {
      acc[2][n] = __builtin_amdgcn_mfma_f32_16x16x32_bf16(a0, b[n], acc[2][n], 0, 0, 0);
      acc[3][n] = __builtin_amdgcn_mfma_f32_16x16x32_bf16(a1, b[n], acc[3][n], 0, 0, 0);
    }
    __builtin_amdgcn_s_setprio(0);
    asm volatile("s_waitcnt vmcnt(0)" ::: "memory");
    __builtin_amdgcn_s_barrier();
  }

  if (MODE == 0) {
    float* outp = (float*)Cv;
    #pragma unroll
    for (int mi = 0; mi < 4; ++mi)
      #pragma unroll
      for (int n = 0; n < 6; ++n)
        #pragma unroll
        for (int rr = 0; rr < 4; ++rr) {
          const size_t idx = (size_t)(row0 + wm + mi * 16 + g * 4 + rr) * (size_t)N
                           + (col0 + wn + n * 16 + r);
          outp[idx] = acc[mi][n][rr];
        }
  } else {
    unsigned short* outp = (unsigned short*)Cv;
    const int hc0 = col0 + wn;               // head-aligned (multiple of 96)
    if (hc0 < 3840) {                        // Q or K head: fused RoPE
      #pragma unroll
      for (int mi = 0; mi < 4; ++mi)
        #pragma unroll
        for (int rr = 0; rr < 4; ++rr) {
          const int row = row0 + wm + mi * 16 + g * 4 + rr;
          const int cb = row * 96;
          const size_t rb = (size_t)row * N + hc0;
          #pragma unroll
          for (int n = 0; n < 3; ++n) {
            const int d = n * 16 + r;
            const float x1 = acc[mi][n][rr], x2 = acc[mi][n + 3][rr];
            const float c1 = cs[cb + d], s1 = sn[cb + d];
            const float c2 = cs[cb + d + 48], s2 = sn[cb + d + 48];
            outp[rb + d]      = f2bf(x1 * c1 - x2 * s1);
            outp[rb + d + 48] = f2bf(x2 * c2 + x1 * s2);
          }
        }
    } else {                                 // V head: plain bf16
      #pragma unroll
      for (int mi = 0; mi < 4; ++mi)
        #pragma unroll
        for (int n = 0; n < 6; ++n)
          #pragma unroll
          for (int rr = 0; rr < 4; ++rr) {
            const size_t idx = (size_t)(row0 + wm + mi * 16 + g * 4 + rr) * (size_t)N
                             + (col0 + wn + n * 16 + r);
            outp[idx] = f2bf(acc[mi][n][rr]);
          }
    }
  }
}

// ---------------- V transpose: qkv[b,s,3840+kvh*96+d] -> vt[b,kvh,d,s] ----------------
__global__ __launch_bounds__(256) void vtrans(const unsigned short* __restrict__ qkv,
                                              unsigned short* __restrict__ vt) {
  __shared__ __align__(16) unsigned short T[64 * 104];
  const int s0 = blockIdx.x * 64;
  const int kvh = blockIdx.y, b = blockIdx.z;
  const int tid = threadIdx.x;
  #pragma unroll
  for (int it = 0; it < 3; ++it) {
    const int c = it * 256 + tid;
    const int sr = c / 12, d0 = (c % 12) * 8;
    *(u32x4*)&T[sr * 104 + d0] =
        *(const u32x4*)&qkv[(size_t)(b * 2048 + s0 + sr) * 4608 + 3840 + kvh * 96 + d0];
  }
  __syncthreads();
  #pragma unroll
  for (int it = 0; it < 3; ++it) {
    const int c = it * 256 + tid;
    const int dr = c >> 3, k0 = (c & 7) * 8;
    u16x8 o;
    #pragma unroll
    for (int j = 0; j < 8; ++j) o[j] = T[(k0 + j) * 104 + dr];
    *(u16x8*)&vt[((size_t)(b * 8 + kvh) * 96 + dr) * 2048 + s0 + k0] = o;
  }
}

// ---------------- Flash attention, causal GQA, swapped QK^T ----------------
// r13 = r9 attn with V read straight from global vt (L2-hot: 393KB per
// (b,kvh), all 32 sharing blocks XCD-pinned). K-only LDS staging; LDS 57.3KB
// (K dbuf 24KB + Ps 32KB). Swizzle algebra for V collapses to linear chunks.
__global__ __launch_bounds__(512) void attn_fwd(const unsigned short* __restrict__ qkv,
                                                const unsigned short* __restrict__ vt,
                                                unsigned short* __restrict__ ctx) {
  __shared__ __align__(16) unsigned short SMEM[28672];  // 57,344 B
  const int wg = blockIdx.x;             // 0..255
  const int xcd = wg & 7, j = wg >> 3;   // j 0..31
  const int c = xcd + ((j >> 4) << 3);   // (b,kvh) id, 0..15
  const int b = c >> 3, kvh = c & 7;
  const int rj = j & 15;
  const int h = kvh * 4 + (rj >> 2);
  const int pr = rj & 3;                 // fold pair: qt in {7-pr, pr}
  const int tid = threadIdx.x;
  const int wave = tid >> 6, lane = tid & 63;
  const int g = lane >> 4, r = lane & 15;
  const float kLS = 0.14724445f;         // (1/sqrt(96)) * log2(e)

  const unsigned short* kgbase = qkv + (size_t)(b * 2048) * 4608 + 3072 + kvh * 96;
  const unsigned short* vgbase = vt + (size_t)(b * 8 + kvh) * 96 * 2048;

  // STAGE K tile t into buffer bi: 768 chunks over 512 threads (2 iters)
  auto STAGE = [&](int t, int bi) {
    const int kv0 = t * 64;
    unsigned short* kd = SMEM + bi * 6144;
    #pragma unroll
    for (int i = 0; i < 2; ++i) {
      const int l = i * 512 + tid;
      if (l < 768) {  // K: [dk][row][c], src chunk c^((row>>1)&3)
        const int dk = l >> 8, rem = l & 255;
        const int row = rem >> 2, cc = rem & 3;
        const int csrc = cc ^ ((row >> 1) & 3);
        gload_lds16(kgbase + (size_t)(kv0 + row) * 4608 + dk * 32 + csrc * 8, kd + l * 8);
      }
    }
  };

  #pragma unroll 1
  for (int sel = 0; sel < 2; ++sel) {
    const int qt = sel ? pr : 7 - pr;
    const int nt = qt * 4 + 4;
    const int q0 = qt * 256 + wave * 32;

    __syncthreads();   // protect LDS (prev epilogue reads) before re-staging

    bf16x8 qf[2][3];
    #pragma unroll
    for (int qb = 0; qb < 2; ++qb)
      #pragma unroll
      for (int dk = 0; dk < 3; ++dk)
        qf[qb][dk] = ld_frag(&qkv[(size_t)(b * 2048 + q0 + qb * 16 + r) * 4608 + h * 96 + dk * 32 + g * 8]);

    f32x4 o[6][2] = {};
    float m_[2] = {-1e30f, -1e30f};
    float l_[2] = {0.f, 0.f};

    STAGE(0, 0);
    __syncthreads();

    for (int t = 0; t < nt; ++t) {
      const int cur = t & 1;
      if (t + 1 < nt) STAGE(t + 1, cur ^ 1);
      const int kv0 = t * 64;
      const unsigned short* Ks = SMEM + cur * 6144;
      unsigned short* Ps = SMEM + 12288 + wave * 2048;

      if (kv0 <= q0 + 31) {  // wave has at least one unmasked element
        f32x4 st[4][2] = {};
        #pragma unroll
        for (int dk = 0; dk < 3; ++dk) {
          bf16x8 af[4];
          #pragma unroll
          for (int kb = 0; kb < 4; ++kb)
            af[kb] = ld_frag(&Ks[dk * 2048 + (kb * 16 + r) * 32 + ((g ^ ((r >> 1) & 3)) * 8)]);
          __builtin_amdgcn_s_setprio(1);
          #pragma unroll
          for (int kb = 0; kb < 4; ++kb)
            #pragma unroll
            for (int qb = 0; qb < 2; ++qb)
              st[kb][qb] = __builtin_amdgcn_mfma_f32_16x16x32_bf16(af[kb], qf[qb][dk], st[kb][qb], 0, 0, 0);
          __builtin_amdgcn_s_setprio(0);
        }
        // scale (exp2 domain) + causal mask (k_abs <= q_abs)
        if (kv0 + 63 > q0) {
          #pragma unroll
          for (int kb = 0; kb < 4; ++kb)
            #pragma unroll
            for (int qb = 0; qb < 2; ++qb)
              #pragma unroll
              for (int rr = 0; rr < 4; ++rr) {
                const int ka = kv0 + kb * 16 + g * 4 + rr;
                const int qa = q0 + qb * 16 + r;
                const float s = st[kb][qb][rr] * kLS;
                st[kb][qb][rr] = (ka <= qa) ? s : -1e30f;
              }
        } else {
          #pragma unroll
          for (int kb = 0; kb < 4; ++kb)
            #pragma unroll
            for (int qb = 0; qb < 2; ++qb)
              #pragma unroll
              for (int rr = 0; rr < 4; ++rr)
                st[kb][qb][rr] *= kLS;
        }
        // online softmax (exp2 domain), per lane = its q column; T13 exact defer
        #pragma unroll
        for (int qb = 0; qb < 2; ++qb) {
          float mx = st[0][qb][0];
          #pragma unroll
          for (int kb = 0; kb < 4; ++kb)
            #pragma unroll
            for (int rr = 0; rr < 4; ++rr) mx = fmaxf(mx, st[kb][qb][rr]);
          mx = fmaxf(mx, __shfl_xor(mx, 16));
          mx = fmaxf(mx, __shfl_xor(mx, 32));
          if (__all(mx <= m_[qb])) {
            float rs = 0.f;
            #pragma unroll
            for (int kb = 0; kb < 4; ++kb)
              #pragma unroll
              for (int rr = 0; rr < 4; ++rr) {
                const float p = __builtin_amdgcn_exp2f(st[kb][qb][rr] - m_[qb]);
                st[kb][qb][rr] = p;
                rs += p;
              }
            rs += __shfl_xor(rs, 16);
            rs += __shfl_xor(rs, 32);
            l_[qb] += rs;
          } else {
            const float mnew = fmaxf(m_[qb], mx);
            const float corr = __builtin_amdgcn_exp2f(m_[qb] - mnew);
            m_[qb] = mnew;
            float rs = 0.f;
            #pragma unroll
            for (int kb = 0; kb < 4; ++kb)
              #pragma unroll
              for (int rr = 0; rr < 4; ++rr) {
                const float p = __builtin_amdgcn_exp2f(st[kb][qb][rr] - mnew);
                st[kb][qb][rr] = p;
                rs += p;
              }
            rs += __shfl_xor(rs, 16);
            rs += __shfl_xor(rs, 32);
            l_[qb] = l_[qb] * corr + rs;
            #pragma unroll
            for (int db = 0; db < 6; ++db) o[db][qb] *= corr;
          }
        }
        // P[q][k] (bf16) to per-wave LDS, swizzled
        #pragma unroll
        for (int kb = 0; kb < 4; ++kb)
          #pragma unroll
          for (int qb = 0; qb < 2; ++qb) {
            u16x4 w;
            #pragma unroll
            for (int rr = 0; rr < 4; ++rr) w[rr] = f2bf(st[kb][qb][rr]);
            const int q = qb * 16 + r;
            *(u16x4*)&Ps[q * 64 + (((2 * kb + (g >> 1)) ^ (r & 7)) << 3) + (g & 1) * 4] = w;
          }
        // O^T += V^T * P^T   (V fragments from global vt — XCD-pinned L2)
        #pragma unroll
        for (int kk = 0; kk < 2; ++kk) {
          bf16x8 pb[2];
          #pragma unroll
          for (int qb = 0; qb < 2; ++qb)
            pb[qb] = ld_frag(&Ps[(qb * 16 + r) * 64 + ((kk * 4 + g) ^ (r & 7)) * 8]);
          __builtin_amdgcn_s_setprio(1);
          #pragma unroll
          for (int db = 0; db < 6; ++db) {
            const bf16x8 va = ld_frag(vgbase + (size_t)(db * 16 + r) * 2048 + kv0 + (kk * 4 + g) * 8);
            #pragma unroll
            for (int qb = 0; qb < 2; ++qb)
              o[db][qb] = __builtin_amdgcn_mfma_f32_16x16x32_bf16(va, pb[qb], o[db][qb], 0, 0, 0);
          }
          __builtin_amdgcn_s_setprio(0);
        }
      }
      __syncthreads();
    }

    // epilogue: normalize, transpose through LDS (per-wave region), coalesced stores
    const float inv_l[2] = {1.f / l_[0], 1.f / l_[1]};
    unsigned short* obuf = SMEM + wave * 3328;  // 32 x 104 per wave (26,624 <= 28,672)
    #pragma unroll
    for (int db = 0; db < 6; ++db)
      #pragma unroll
      for (int qb = 0; qb < 2; ++qb) {
        u16x4 w;
        #pragma unroll
        for (int rr = 0; rr < 4; ++rr) w[rr] = f2bf(o[db][qb][rr] * inv_l[qb]);
        *(u16x4*)&obuf[(qb * 16 + r) * 104 + db * 16 + g * 4] = w;
      }
    #pragma unroll
    for (int it = 0; it < 6; ++it) {
      const int cc = it * 64 + lane;
      const int qr = cc / 12, d0 = (cc % 12) * 8;
      *(u32x4*)&ctx[(size_t)(b * 2048 + q0 + qr) * 3072 + h * 96 + d0] =
          *(const u32x4*)&obuf[qr * 104 + d0];
    }
  }
}

extern "C" void kernel_launch(void* const* d_in, const int* in_sizes, int n_in,
                              void* d_out, int out_size, void* d_ws, size_t ws_size,
                              hipStream_t stream) {
  const float* hs   = (const float*)d_in[0];
  const float* cosp = (const float*)d_in[1];
  const float* sinp = (const float*)d_in[2];
  const float* wqkv = (const float*)d_in[4];
  const float* wo   = (const float*)d_in[5];
  float* out = (float*)d_out;

  // workspace layout (bf16 elems): qkv 18,874,368 | hsb 12,582,912 | wqb 14,155,776
  // after GEMM1: hsb region reused as vt (3,145,728) + wob (9,437,184); wqb as ctx.
  unsigned short* qkv = (unsigned short*)d_ws;
  unsigned short* hsb = qkv + 18874368;
  unsigned short* wqb = hsb + 12582912;
  unsigned short* vt  = hsb;
  unsigned short* wob = hsb + 3145728;
  unsigned short* ctx = wqb;

  cvt_bf16<<<12288, 256, 0, stream>>>(hs,   hsb, 3145728);
  cvt_bf16<<<13824, 256, 0, stream>>>(wqkv, wqb, 3538944);
  gemm8p<1><<<384, 512, 0, stream>>>(hsb, wqb, (void*)qkv, cosp, sinp, 4096, 4608, 3072);
  vtrans<<<dim3(32, 8, 2), 256, 0, stream>>>(qkv, vt);
  cvt_bf16<<<9216, 256, 0, stream>>>(wo, wob, 2359296);
  attn_fwd<<<256, 512, 0, stream>>>(qkv, vt, ctx);
  gemm8p<0><<<256, 512, 0, stream>>>(ctx, wob, (void*)out, cosp, sinp, 4096, 3072, 3072);
}